// Round 1
// baseline (1182.815 us; speedup 1.0000x reference)
//
#include <hip/hip_runtime.h>
#include <cstddef>

#define D 256
#define H 8
#define HD 32
#define ED 64
#define KC 4
#define EPB 32

// ---------------- activations ----------------
template<int ACT> __device__ inline float act_f(float v) {
    if (ACT == 1) return fmaxf(v, 0.f);
    if (ACT == 2) return v > 0.f ? v : expm1f(v);              // elu
    if (ACT == 3) return 0.5f * v * (1.f + erff(v * 0.70710678118654752f)); // exact gelu
    return v;
}

__device__ inline float wave_sum(float v) {
#pragma unroll
    for (int off = 32; off > 0; off >>= 1) v += __shfl_xor(v, off, 64);
    return v;
}

// ---------------- h = (1+eps)*x ----------------
__global__ void init_h_kernel(const float* __restrict__ x, const float* __restrict__ eps,
                              float* __restrict__ h, int total) {
    int i = blockIdx.x * 256 + threadIdx.x;
    if (i < total) h[i] = (1.f + eps[0]) * x[i];
}

// ---------------- GINE edge kernel: msg = relu(x[src] + ea@Wl + bl), atomic scatter to h[dst]
__global__ __launch_bounds__(256) void edge_kernel(
        const float* __restrict__ x, const int* __restrict__ ei,
        const float* __restrict__ ea, const float* __restrict__ Wl,
        const float* __restrict__ bl, float* __restrict__ h, int E) {
    __shared__ float s_ea[EPB][ED];
    __shared__ int s_src[EPB], s_dst[EPB];
    int tid = threadIdx.x;
    int e0 = blockIdx.x * EPB;
    // Wl column d=tid into registers
    float w[ED];
#pragma unroll
    for (int k = 0; k < ED; k++) w[k] = Wl[k * D + tid];
    float bld = bl[tid];
    for (int i = tid; i < EPB * ED; i += 256) {
        int e = i >> 6, c = i & 63;
        s_ea[e][c] = ea[(size_t)(e0 + e) * ED + c];
    }
    if (tid < EPB) { s_src[tid] = ei[e0 + tid]; s_dst[tid] = ei[E + e0 + tid]; }
    __syncthreads();
    for (int i = 0; i < EPB; i++) {
        const float4* eap = (const float4*)&s_ea[i][0];
        float v = bld;
#pragma unroll
        for (int k4 = 0; k4 < ED / 4; k4++) {
            float4 e4 = eap[k4];
            v += e4.x * w[k4 * 4] + e4.y * w[k4 * 4 + 1] + e4.z * w[k4 * 4 + 2] + e4.w * w[k4 * 4 + 3];
        }
        float m = v + x[(size_t)s_src[i] * D + tid];
        m = fmaxf(m, 0.f);
        atomicAdd(&h[(size_t)s_dst[i] * D + tid], m);
    }
}

// ---------------- generic fp32 GEMM: C[M,Nc] = act(A[M,K] @ B + bias) ----------------
// TRANSB=false: B is [K,Nc] row-major. TRANSB=true: B is [Nc,K] row-major (C = A @ B^T).
#define BM 64
#define BN 64
#define BK 16
template<int ACT, bool TRANSB>
__global__ __launch_bounds__(256) void gemm_kernel(
        const float* __restrict__ A, const float* __restrict__ B,
        const float* __restrict__ bias, float* __restrict__ C,
        int M, int K, int Nc) {
    __shared__ float As[BK][BM + 4];
    __shared__ float Bs[BK][BN + 4];
    int tid = threadIdx.x;
    int m0 = blockIdx.y * BM, n0 = blockIdx.x * BN;
    int tm = (tid >> 4) * 4, tn = (tid & 15) * 4;
    float acc[4][4] = {};
    for (int k0 = 0; k0 < K; k0 += BK) {
        int ac = tid & 15, ar = tid >> 4;
#pragma unroll
        for (int p = 0; p < 4; p++)
            As[ac][ar + p * 16] = A[(size_t)(m0 + ar + p * 16) * K + k0 + ac];
        if (TRANSB) {
            int bk = tid & 15, bj = tid >> 4;
#pragma unroll
            for (int p = 0; p < 4; p++)
                Bs[bk][bj + p * 16] = B[(size_t)(n0 + bj + p * 16) * K + k0 + bk];
        } else {
            int bj = tid & 63, bk = tid >> 6;
#pragma unroll
            for (int p = 0; p < 4; p++)
                Bs[bk + p * 4][bj] = B[(size_t)(k0 + bk + p * 4) * Nc + n0 + bj];
        }
        __syncthreads();
#pragma unroll
        for (int k = 0; k < BK; k++) {
            float4 a4 = *(const float4*)&As[k][tm];
            float4 b4 = *(const float4*)&Bs[k][tn];
            float a[4] = {a4.x, a4.y, a4.z, a4.w};
            float b[4] = {b4.x, b4.y, b4.z, b4.w};
#pragma unroll
            for (int i = 0; i < 4; i++)
#pragma unroll
                for (int j = 0; j < 4; j++) acc[i][j] += a[i] * b[j];
        }
        __syncthreads();
    }
#pragma unroll
    for (int i = 0; i < 4; i++) {
        float4 r;
        r.x = act_f<ACT>(acc[i][0] + bias[n0 + tn + 0]);
        r.y = act_f<ACT>(acc[i][1] + bias[n0 + tn + 1]);
        r.z = act_f<ACT>(acc[i][2] + bias[n0 + tn + 2]);
        r.w = act_f<ACT>(acc[i][3] + bias[n0 + tn + 3]);
        *(float4*)&C[(size_t)(m0 + tm + i) * Nc + n0 + tn] = r;
    }
}

// ---------------- row LayerNorm + optional ELU + residual: out = res + act(ln(t)*g+b) --------
template<int ACT>
__global__ __launch_bounds__(256) void ln_res_kernel(
        const float* __restrict__ t, const float* __restrict__ res,
        const float* __restrict__ g, const float* __restrict__ b,
        float* __restrict__ out) {
    __shared__ float red[8];
    int row = blockIdx.x, tid = threadIdx.x;
    float v = t[(size_t)row * D + tid];
    int wid = tid >> 6, lane = tid & 63;
    float s = wave_sum(v);
    if (lane == 0) red[wid] = s;
    __syncthreads();
    float mu = (red[0] + red[1] + red[2] + red[3]) * (1.f / D);
    float dv = v - mu;
    float s2 = wave_sum(dv * dv);
    if (lane == 0) red[4 + wid] = s2;
    __syncthreads();
    float var = (red[4] + red[5] + red[6] + red[7]) * (1.f / D);
    float y = dv * rsqrtf(var + 1e-5f) * g[tid] + b[tid];
    y = act_f<ACT>(y);
    out[(size_t)row * D + tid] = res[(size_t)row * D + tid] + y;
}

// ---------------- flash attention, split-K partials ----------------
// qkv: [N, 768]; q at +0, k at +256, v at +512, head h at h*32.
// grid: (N/64, H, KC), block 64. Each thread: one q row. Partials po/pm/pl.
#define BKK 64
__global__ __launch_bounds__(64) void attn_partial_kernel(
        const float* __restrict__ qkv, float* __restrict__ po,
        float* __restrict__ pm, float* __restrict__ pl, int N) {
    __shared__ float kT[BKK][HD];
    __shared__ float vT[BKK][HD];
    int tid = threadIdx.x;
    int qi = blockIdx.x * 64 + tid;
    int h = blockIdx.y;
    int c = blockIdx.z;
    float q[HD], o[HD];
    const float* qrow = qkv + (size_t)qi * (3 * D) + h * HD;
#pragma unroll
    for (int d4 = 0; d4 < HD / 4; d4++) {
        float4 t = *(const float4*)(qrow + d4 * 4);
        q[d4 * 4] = t.x; q[d4 * 4 + 1] = t.y; q[d4 * 4 + 2] = t.z; q[d4 * 4 + 3] = t.w;
    }
#pragma unroll
    for (int d = 0; d < HD; d++) o[d] = 0.f;
    float m = -1e30f, l = 0.f;
    const float scale = 0.17677669529663687f; // 1/sqrt(32)
    int kchunk = N / KC;
    int kstart = c * kchunk, kend = kstart + kchunk;
    for (int k0 = kstart; k0 < kend; k0 += BKK) {
#pragma unroll
        for (int p = 0; p < 8; p++) {
            int idx = tid + p * 64;          // 0..511 float4 slots
            int kr = idx >> 3, d4 = idx & 7;
            const float* kbase = qkv + (size_t)(k0 + kr) * (3 * D) + D + h * HD;
            const float* vbase = qkv + (size_t)(k0 + kr) * (3 * D) + 2 * D + h * HD;
            ((float4*)&kT[kr][0])[d4] = ((const float4*)kbase)[d4];
            ((float4*)&vT[kr][0])[d4] = ((const float4*)vbase)[d4];
        }
        __syncthreads();
        for (int j = 0; j < BKK; j++) {
            const float4* kp = (const float4*)&kT[j][0];
            float s = 0.f;
#pragma unroll
            for (int d4 = 0; d4 < HD / 4; d4++) {
                float4 kk = kp[d4];
                s += q[d4 * 4] * kk.x + q[d4 * 4 + 1] * kk.y + q[d4 * 4 + 2] * kk.z + q[d4 * 4 + 3] * kk.w;
            }
            s *= scale;
            float nm = fmaxf(m, s);
            float alpha = __expf(m - nm);
            float p = __expf(s - nm);
            l = l * alpha + p;
            const float4* vp = (const float4*)&vT[j][0];
#pragma unroll
            for (int d4 = 0; d4 < HD / 4; d4++) {
                float4 vv = vp[d4];
                o[d4 * 4]     = o[d4 * 4]     * alpha + p * vv.x;
                o[d4 * 4 + 1] = o[d4 * 4 + 1] * alpha + p * vv.y;
                o[d4 * 4 + 2] = o[d4 * 4 + 2] * alpha + p * vv.z;
                o[d4 * 4 + 3] = o[d4 * 4 + 3] * alpha + p * vv.w;
            }
            m = nm;
        }
        __syncthreads();
    }
    size_t nh = (size_t)qi * H + h;
    size_t NH = (size_t)N * H;
    pm[(size_t)c * NH + nh] = m;
    pl[(size_t)c * NH + nh] = l;
    float* op = po + ((size_t)c * NH + nh) * HD;
#pragma unroll
    for (int d4 = 0; d4 < HD / 4; d4++) {
        float4 r; r.x = o[d4 * 4]; r.y = o[d4 * 4 + 1]; r.z = o[d4 * 4 + 2]; r.w = o[d4 * 4 + 3];
        *(float4*)(op + d4 * 4) = r;
    }
}

// ---------------- combine partials -> obuf[N, 256] ----------------
__global__ __launch_bounds__(256) void attn_combine_kernel(
        const float* __restrict__ po, const float* __restrict__ pm,
        const float* __restrict__ pl, float* __restrict__ obuf, int N) {
    int idx = blockIdx.x * 256 + threadIdx.x;   // over N*H*HD
    int d = idx & (HD - 1);
    int nh = idx >> 5;
    size_t NH = (size_t)N * H;
    float mv[KC];
    float M = -1e30f;
#pragma unroll
    for (int cc = 0; cc < KC; cc++) { mv[cc] = pm[(size_t)cc * NH + nh]; M = fmaxf(M, mv[cc]); }
    float l = 0.f, o = 0.f;
#pragma unroll
    for (int cc = 0; cc < KC; cc++) {
        float a = __expf(mv[cc] - M);
        l += a * pl[(size_t)cc * NH + nh];
        o += a * po[((size_t)cc * NH + nh) * HD + d];
    }
    int n = nh >> 3, h = nh & (H - 1);
    obuf[(size_t)n * D + h * HD + d] = o / l;
}

// ---------------- launch ----------------
extern "C" void kernel_launch(void* const* d_in, const int* in_sizes, int n_in,
                              void* d_out, int out_size, void* d_ws, size_t ws_size,
                              hipStream_t stream) {
    const float* x    = (const float*)d_in[0];
    const int*   ei   = (const int*)d_in[1];
    const float* ea   = (const float*)d_in[2];
    const float* eps  = (const float*)d_in[3];
    const float* Wl   = (const float*)d_in[4];
    const float* bl   = (const float*)d_in[5];
    const float* W1   = (const float*)d_in[6];
    const float* b1   = (const float*)d_in[7];
    const float* W2   = (const float*)d_in[8];
    const float* b2   = (const float*)d_in[9];
    const float* lnlg = (const float*)d_in[10];
    const float* lnlb = (const float*)d_in[11];
    const float* in_w = (const float*)d_in[12];
    const float* in_b = (const float*)d_in[13];
    const float* outw = (const float*)d_in[14];
    const float* outb = (const float*)d_in[15];
    const float* lnag = (const float*)d_in[16];
    const float* lnab = (const float*)d_in[17];
    const float* Wf1  = (const float*)d_in[18];
    const float* bf1  = (const float*)d_in[19];
    const float* Wf2  = (const float*)d_in[20];
    const float* bf2  = (const float*)d_in[21];
    const float* lnfg = (const float*)d_in[22];
    const float* lnfb = (const float*)d_in[23];
    float* out = (float*)d_out;

    const int N = in_sizes[0] / D;       // 4096
    const int E = in_sizes[1] / 2;       // 262144
    const size_t NF = (size_t)N * D;     // 1048576

    float* w = (float*)d_ws;
    float* h    = w + 0;          // NF     (also obuf, f2 later)
    float* t1   = w + NF;         // NF     (also t3)
    float* t2   = w + 2 * NF;     // NF     (also x2)
    float* x1   = w + 3 * NF;     // NF
    float* qkv  = w + 4 * NF;     // 3*NF   (also f1: 2*NF)
    float* po   = w + 7 * NF;     // KC*N*H*HD = 4*NF
    float* pm   = w + 11 * NF;    // KC*N*H
    float* pl   = pm + (size_t)KC * N * H;
    float* obuf = h;
    float* t3   = t1;
    float* x2   = t2;
    float* f1   = qkv;
    float* f2   = h;

    // 1. h = (1+eps)*x
    init_h_kernel<<<(int)(NF / 256), 256, 0, stream>>>(x, eps, h, (int)NF);
    // 2. GINE scatter
    edge_kernel<<<E / EPB, 256, 0, stream>>>(x, ei, ea, Wl, bl, h, E);
    // 3. t1 = elu(h@W1+b1)
    gemm_kernel<2, false><<<dim3(D / BN, N / BM), 256, 0, stream>>>(h, W1, b1, t1, N, D, D);
    // 4. t2 = t1@W2+b2
    gemm_kernel<0, false><<<dim3(D / BN, N / BM), 256, 0, stream>>>(t1, W2, b2, t2, N, D, D);
    // 5. x1 = x + elu(ln(t2))
    ln_res_kernel<2><<<N, 256, 0, stream>>>(t2, x, lnlg, lnlb, x1);
    // 6. qkv = x1 @ in_w.T + in_b
    gemm_kernel<0, true><<<dim3(3 * D / BN, N / BM), 256, 0, stream>>>(x1, in_w, in_b, qkv, N, D, 3 * D);
    // 7. attention partials
    attn_partial_kernel<<<dim3(N / 64, H, KC), 64, 0, stream>>>(qkv, po, pm, pl, N);
    // 8. combine
    attn_combine_kernel<<<(int)(NF / 256), 256, 0, stream>>>(po, pm, pl, obuf, N);
    // 9. t3 = obuf @ out_w.T + out_b
    gemm_kernel<0, true><<<dim3(D / BN, N / BM), 256, 0, stream>>>(obuf, outw, outb, t3, N, D, D);
    // 10. x2 = x1 + ln(t3)
    ln_res_kernel<0><<<N, 256, 0, stream>>>(t3, x1, lnag, lnab, x2);
    // 11. f1 = gelu(x2@Wf1+bf1)
    gemm_kernel<3, false><<<dim3(2 * D / BN, N / BM), 256, 0, stream>>>(x2, Wf1, bf1, f1, N, D, 2 * D);
    // 12. f2 = f1@Wf2+bf2
    gemm_kernel<0, false><<<dim3(D / BN, N / BM), 256, 0, stream>>>(f1, Wf2, bf2, f2, N, 2 * D, D);
    // 13. out = x2 + ln(f2)
    ln_res_kernel<0><<<N, 256, 0, stream>>>(f2, x2, lnfg, lnfb, out);

    (void)n_in; (void)out_size; (void)ws_size;
}

// Round 2
// 1045.002 us; speedup vs baseline: 1.1319x; 1.1319x over previous
//
#include <hip/hip_runtime.h>
#include <cstddef>

#define D 256
#define H 8
#define HD 32
#define ED 64
#define EPB 32

// ---------------- activations ----------------
template<int ACT> __device__ inline float act_f(float v) {
    if (ACT == 1) return fmaxf(v, 0.f);
    if (ACT == 2) return v > 0.f ? v : expm1f(v);              // elu
    if (ACT == 3) return 0.5f * v * (1.f + erff(v * 0.70710678118654752f)); // exact gelu
    return v;
}

__device__ inline float wave_sum(float v) {
#pragma unroll
    for (int off = 32; off > 0; off >>= 1) v += __shfl_xor(v, off, 64);
    return v;
}

// ---------------- h = (1+eps)*x ----------------
__global__ void init_h_kernel(const float* __restrict__ x, const float* __restrict__ eps,
                              float* __restrict__ h, int total) {
    int i = blockIdx.x * 256 + threadIdx.x;
    if (i < total) h[i] = (1.f + eps[0]) * x[i];
}

// ---------------- GINE edge kernel: msg = relu(x[src] + ea@Wl + bl), atomic scatter to h[dst]
__global__ __launch_bounds__(256) void edge_kernel(
        const float* __restrict__ x, const int* __restrict__ ei,
        const float* __restrict__ ea, const float* __restrict__ Wl,
        const float* __restrict__ bl, float* __restrict__ h, int E) {
    __shared__ float s_ea[EPB][ED];
    __shared__ int s_src[EPB], s_dst[EPB];
    int tid = threadIdx.x;
    int e0 = blockIdx.x * EPB;
    float w[ED];
#pragma unroll
    for (int k = 0; k < ED; k++) w[k] = Wl[k * D + tid];
    float bld = bl[tid];
    for (int i = tid; i < EPB * ED; i += 256) {
        int e = i >> 6, c = i & 63;
        s_ea[e][c] = ea[(size_t)(e0 + e) * ED + c];
    }
    if (tid < EPB) { s_src[tid] = ei[e0 + tid]; s_dst[tid] = ei[E + e0 + tid]; }
    __syncthreads();
    for (int i = 0; i < EPB; i++) {
        const float4* eap = (const float4*)&s_ea[i][0];
        float v = bld;
#pragma unroll
        for (int k4 = 0; k4 < ED / 4; k4++) {
            float4 e4 = eap[k4];
            v += e4.x * w[k4 * 4] + e4.y * w[k4 * 4 + 1] + e4.z * w[k4 * 4 + 2] + e4.w * w[k4 * 4 + 3];
        }
        float m = v + x[(size_t)s_src[i] * D + tid];
        m = fmaxf(m, 0.f);
        atomicAdd(&h[(size_t)s_dst[i] * D + tid], m);
    }
}

// ---------------- generic fp32 GEMM ----------------
#define BM 64
#define BN 64
#define BK 16
template<int ACT, bool TRANSB>
__global__ __launch_bounds__(256) void gemm_kernel(
        const float* __restrict__ A, const float* __restrict__ B,
        const float* __restrict__ bias, float* __restrict__ C,
        int M, int K, int Nc) {
    __shared__ float As[BK][BM + 4];
    __shared__ float Bs[BK][BN + 4];
    int tid = threadIdx.x;
    int m0 = blockIdx.y * BM, n0 = blockIdx.x * BN;
    int tm = (tid >> 4) * 4, tn = (tid & 15) * 4;
    float acc[4][4] = {};
    for (int k0 = 0; k0 < K; k0 += BK) {
        int ac = tid & 15, ar = tid >> 4;
#pragma unroll
        for (int p = 0; p < 4; p++)
            As[ac][ar + p * 16] = A[(size_t)(m0 + ar + p * 16) * K + k0 + ac];
        if (TRANSB) {
            int bk = tid & 15, bj = tid >> 4;
#pragma unroll
            for (int p = 0; p < 4; p++)
                Bs[bk][bj + p * 16] = B[(size_t)(n0 + bj + p * 16) * K + k0 + bk];
        } else {
            int bj = tid & 63, bk = tid >> 6;
#pragma unroll
            for (int p = 0; p < 4; p++)
                Bs[bk + p * 4][bj] = B[(size_t)(k0 + bk + p * 4) * Nc + n0 + bj];
        }
        __syncthreads();
#pragma unroll
        for (int k = 0; k < BK; k++) {
            float4 a4 = *(const float4*)&As[k][tm];
            float4 b4 = *(const float4*)&Bs[k][tn];
            float a[4] = {a4.x, a4.y, a4.z, a4.w};
            float b[4] = {b4.x, b4.y, b4.z, b4.w};
#pragma unroll
            for (int i = 0; i < 4; i++)
#pragma unroll
                for (int j = 0; j < 4; j++) acc[i][j] += a[i] * b[j];
        }
        __syncthreads();
    }
#pragma unroll
    for (int i = 0; i < 4; i++) {
        float4 r;
        r.x = act_f<ACT>(acc[i][0] + bias[n0 + tn + 0]);
        r.y = act_f<ACT>(acc[i][1] + bias[n0 + tn + 1]);
        r.z = act_f<ACT>(acc[i][2] + bias[n0 + tn + 2]);
        r.w = act_f<ACT>(acc[i][3] + bias[n0 + tn + 3]);
        *(float4*)&C[(size_t)(m0 + tm + i) * Nc + n0 + tn] = r;
    }
}

// ---------------- row LayerNorm + optional ELU + residual ----------------
template<int ACT>
__global__ __launch_bounds__(256) void ln_res_kernel(
        const float* __restrict__ t, const float* __restrict__ res,
        const float* __restrict__ g, const float* __restrict__ b,
        float* __restrict__ out) {
    __shared__ float red[8];
    int row = blockIdx.x, tid = threadIdx.x;
    float v = t[(size_t)row * D + tid];
    int wid = tid >> 6, lane = tid & 63;
    float s = wave_sum(v);
    if (lane == 0) red[wid] = s;
    __syncthreads();
    float mu = (red[0] + red[1] + red[2] + red[3]) * (1.f / D);
    float dv = v - mu;
    float s2 = wave_sum(dv * dv);
    if (lane == 0) red[4 + wid] = s2;
    __syncthreads();
    float var = (red[4] + red[5] + red[6] + red[7]) * (1.f / D);
    float y = dv * rsqrtf(var + 1e-5f) * g[tid] + b[tid];
    y = act_f<ACT>(y);
    out[(size_t)row * D + tid] = res[(size_t)row * D + tid] + y;
}

// ---------------- flash attention, split-K partials ----------------
// block 256 (4 waves), each thread owns one q row. K/V tile in LDS shared by
// all 4 waves; tile reads are lane-uniform -> LDS broadcast. Deferred-rescale
// online softmax: batch STILE scores, one rescale per batch.
#define BKK 64
#define STILE 16
__global__ __launch_bounds__(256) void attn_partial_kernel(
        const float* __restrict__ qkv, float* __restrict__ po,
        float* __restrict__ pm, float* __restrict__ pl, int N, int KC_) {
    __shared__ float kT[BKK][HD];
    __shared__ float vT[BKK][HD];
    int tid = threadIdx.x;
    int qi = blockIdx.x * 256 + tid;
    int h = blockIdx.y;
    int c = blockIdx.z;
    float q[HD], o[HD];
    const float* qrow = qkv + (size_t)qi * (3 * D) + h * HD;
#pragma unroll
    for (int d4 = 0; d4 < HD / 4; d4++) {
        float4 t = *(const float4*)(qrow + d4 * 4);
        q[d4 * 4] = t.x; q[d4 * 4 + 1] = t.y; q[d4 * 4 + 2] = t.z; q[d4 * 4 + 3] = t.w;
    }
#pragma unroll
    for (int d = 0; d < HD; d++) o[d] = 0.f;
    float m = -1e30f, l = 0.f;
    const float scale = 0.17677669529663687f; // 1/sqrt(32)
    int kchunk = N / KC_;
    int kstart = c * kchunk, kend = kstart + kchunk;
    for (int k0 = kstart; k0 < kend; k0 += BKK) {
        // stage K/V tile: 64 rows x 8 float4 = 512 slots each, 2 per thread
#pragma unroll
        for (int p = 0; p < 2; p++) {
            int idx = tid + p * 256;
            int kr = idx >> 3, d4 = idx & 7;
            const float* kbase = qkv + (size_t)(k0 + kr) * (3 * D) + D + h * HD;
            const float* vbase = qkv + (size_t)(k0 + kr) * (3 * D) + 2 * D + h * HD;
            ((float4*)&kT[kr][0])[d4] = ((const float4*)kbase)[d4];
            ((float4*)&vT[kr][0])[d4] = ((const float4*)vbase)[d4];
        }
        __syncthreads();
#pragma unroll
        for (int jt = 0; jt < BKK; jt += STILE) {
            float s[STILE];
            // 16 independent dot products (LDS reads are broadcast)
#pragma unroll
            for (int jj = 0; jj < STILE; jj++) {
                const float4* kp = (const float4*)&kT[jt + jj][0];
                float acc0 = 0.f, acc1 = 0.f;
#pragma unroll
                for (int d4 = 0; d4 < HD / 4; d4 += 2) {
                    float4 k0v = kp[d4], k1v = kp[d4 + 1];
                    acc0 += q[d4 * 4] * k0v.x + q[d4 * 4 + 1] * k0v.y + q[d4 * 4 + 2] * k0v.z + q[d4 * 4 + 3] * k0v.w;
                    acc1 += q[d4 * 4 + 4] * k1v.x + q[d4 * 4 + 5] * k1v.y + q[d4 * 4 + 6] * k1v.z + q[d4 * 4 + 7] * k1v.w;
                }
                s[jj] = (acc0 + acc1) * scale;
            }
            // tile max
            float tmax = s[0];
#pragma unroll
            for (int jj = 1; jj < STILE; jj++) tmax = fmaxf(tmax, s[jj]);
            float nm = fmaxf(m, tmax);
            float alpha = __expf(m - nm);
            l *= alpha;
#pragma unroll
            for (int d = 0; d < HD; d++) o[d] *= alpha;
#pragma unroll
            for (int jj = 0; jj < STILE; jj++) {
                float p_ = __expf(s[jj] - nm);
                l += p_;
                s[jj] = p_;
            }
#pragma unroll
            for (int jj = 0; jj < STILE; jj++) {
                const float4* vp = (const float4*)&vT[jt + jj][0];
#pragma unroll
                for (int d4 = 0; d4 < HD / 4; d4++) {
                    float4 vv = vp[d4];
                    o[d4 * 4]     += s[jj] * vv.x;
                    o[d4 * 4 + 1] += s[jj] * vv.y;
                    o[d4 * 4 + 2] += s[jj] * vv.z;
                    o[d4 * 4 + 3] += s[jj] * vv.w;
                }
            }
            m = nm;
        }
        __syncthreads();
    }
    size_t nh = (size_t)qi * H + h;
    size_t NH = (size_t)N * H;
    pm[(size_t)c * NH + nh] = m;
    pl[(size_t)c * NH + nh] = l;
    float* op = po + ((size_t)c * NH + nh) * HD;
#pragma unroll
    for (int d4 = 0; d4 < HD / 4; d4++) {
        float4 r; r.x = o[d4 * 4]; r.y = o[d4 * 4 + 1]; r.z = o[d4 * 4 + 2]; r.w = o[d4 * 4 + 3];
        *(float4*)(op + d4 * 4) = r;
    }
}

// ---------------- combine partials -> obuf[N, 256] ----------------
__global__ __launch_bounds__(256) void attn_combine_kernel(
        const float* __restrict__ po, const float* __restrict__ pm,
        const float* __restrict__ pl, float* __restrict__ obuf, int N, int KC_) {
    int idx = blockIdx.x * 256 + threadIdx.x;   // over N*H*HD
    int d = idx & (HD - 1);
    int nh = idx >> 5;
    size_t NH = (size_t)N * H;
    float M = -1e30f;
    for (int cc = 0; cc < KC_; cc++) M = fmaxf(M, pm[(size_t)cc * NH + nh]);
    float l = 0.f, o = 0.f;
    for (int cc = 0; cc < KC_; cc++) {
        float a = __expf(pm[(size_t)cc * NH + nh] - M);
        l += a * pl[(size_t)cc * NH + nh];
        o += a * po[((size_t)cc * NH + nh) * HD + d];
    }
    int n = nh >> 3, h = nh & (H - 1);
    obuf[(size_t)n * D + h * HD + d] = o / l;
}

// ---------------- launch ----------------
extern "C" void kernel_launch(void* const* d_in, const int* in_sizes, int n_in,
                              void* d_out, int out_size, void* d_ws, size_t ws_size,
                              hipStream_t stream) {
    const float* x    = (const float*)d_in[0];
    const int*   ei   = (const int*)d_in[1];
    const float* ea   = (const float*)d_in[2];
    const float* eps  = (const float*)d_in[3];
    const float* Wl   = (const float*)d_in[4];
    const float* bl   = (const float*)d_in[5];
    const float* W1   = (const float*)d_in[6];
    const float* b1   = (const float*)d_in[7];
    const float* W2   = (const float*)d_in[8];
    const float* b2   = (const float*)d_in[9];
    const float* lnlg = (const float*)d_in[10];
    const float* lnlb = (const float*)d_in[11];
    const float* in_w = (const float*)d_in[12];
    const float* in_b = (const float*)d_in[13];
    const float* outw = (const float*)d_in[14];
    const float* outb = (const float*)d_in[15];
    const float* lnag = (const float*)d_in[16];
    const float* lnab = (const float*)d_in[17];
    const float* Wf1  = (const float*)d_in[18];
    const float* bf1  = (const float*)d_in[19];
    const float* Wf2  = (const float*)d_in[20];
    const float* bf2  = (const float*)d_in[21];
    const float* lnfg = (const float*)d_in[22];
    const float* lnfb = (const float*)d_in[23];
    float* out = (float*)d_out;

    const int N = in_sizes[0] / D;       // 4096
    const int E = in_sizes[1] / 2;       // 262144
    const size_t NF = (size_t)N * D;     // 1048576

    // Split-K factor for attention: 8 if workspace allows, else 4.
    auto need_bytes = [&](int kc) -> size_t {
        return ((size_t)(4 + kc) * NF + 2 * (size_t)kc * N * H) * sizeof(float);
    };
    int KCsel = (ws_size >= need_bytes(8)) ? 8 : 4;

    float* w = (float*)d_ws;
    // layout (units of NF floats):
    //   x1   = 0
    //   qkv  = 1..4            (obuf,t3,x2 reuse this region after attention)
    //   h,t1,t2 = 4,5,6        (dead before po is written)
    //   po   = 4..4+KC
    //   pm   = 4+KC .., pl follows
    //   f1   = 4..6 (po dead), f2 = 6
    float* x1   = w;
    float* qkv  = w + NF;
    float* h    = w + 4 * NF;
    float* t1   = w + 5 * NF;
    float* t2   = w + 6 * NF;
    float* po   = w + 4 * NF;
    float* pm   = w + (4 + (size_t)KCsel) * NF;
    float* pl   = pm + (size_t)KCsel * N * H;
    float* obuf = w + NF;
    float* t3   = w + 2 * NF;
    float* x2   = w + 3 * NF;
    float* f1   = w + 4 * NF;
    float* f2   = w + 6 * NF;

    // 1. h = (1+eps)*x
    init_h_kernel<<<(int)(NF / 256), 256, 0, stream>>>(x, eps, h, (int)NF);
    // 2. GINE scatter
    edge_kernel<<<E / EPB, 256, 0, stream>>>(x, ei, ea, Wl, bl, h, E);
    // 3. t1 = elu(h@W1+b1)
    gemm_kernel<2, false><<<dim3(D / BN, N / BM), 256, 0, stream>>>(h, W1, b1, t1, N, D, D);
    // 4. t2 = t1@W2+b2
    gemm_kernel<0, false><<<dim3(D / BN, N / BM), 256, 0, stream>>>(t1, W2, b2, t2, N, D, D);
    // 5. x1 = x + elu(ln(t2))
    ln_res_kernel<2><<<N, 256, 0, stream>>>(t2, x, lnlg, lnlb, x1);
    // 6. qkv = x1 @ in_w.T + in_b
    gemm_kernel<0, true><<<dim3(3 * D / BN, N / BM), 256, 0, stream>>>(x1, in_w, in_b, qkv, N, D, 3 * D);
    // 7. attention partials
    attn_partial_kernel<<<dim3(N / 256, H, KCsel), 256, 0, stream>>>(qkv, po, pm, pl, N, KCsel);
    // 8. combine
    attn_combine_kernel<<<(int)(NF / 256), 256, 0, stream>>>(po, pm, pl, obuf, N, KCsel);
    // 9. t3 = obuf @ out_w.T + out_b
    gemm_kernel<0, true><<<dim3(D / BN, N / BM), 256, 0, stream>>>(obuf, outw, outb, t3, N, D, D);
    // 10. x2 = x1 + ln(t3)
    ln_res_kernel<0><<<N, 256, 0, stream>>>(t3, x1, lnag, lnab, x2);
    // 11. f1 = gelu(x2@Wf1+bf1)
    gemm_kernel<3, false><<<dim3(2 * D / BN, N / BM), 256, 0, stream>>>(x2, Wf1, bf1, f1, N, D, 2 * D);
    // 12. f2 = f1@Wf2+bf2
    gemm_kernel<0, false><<<dim3(D / BN, N / BM), 256, 0, stream>>>(f1, Wf2, bf2, f2, N, 2 * D, D);
    // 13. out = x2 + ln(f2)
    ln_res_kernel<0><<<N, 256, 0, stream>>>(f2, x2, lnfg, lnfb, out);

    (void)n_in; (void)out_size; (void)ws_size;
}

// Round 3
// 596.087 us; speedup vs baseline: 1.9843x; 1.7531x over previous
//
#include <hip/hip_runtime.h>
#include <cstddef>

#define D 256
#define H 8
#define HD 32
#define ED 64
#define EPB 32

typedef __attribute__((ext_vector_type(8))) short short8;
typedef __attribute__((ext_vector_type(4))) short short4v;
typedef __attribute__((ext_vector_type(4))) float floatx4;

// fp32 -> bf16 RNE
__device__ inline short f2bf(float f) {
    unsigned u = __float_as_uint(f);
    unsigned r = (u + 0x7fffu + ((u >> 16) & 1u)) >> 16;
    return (short)r;
}

// ---------------- activations ----------------
template<int ACT> __device__ inline float act_f(float v) {
    if (ACT == 1) return fmaxf(v, 0.f);
    if (ACT == 2) return v > 0.f ? v : expm1f(v);              // elu
    if (ACT == 3) return 0.5f * v * (1.f + erff(v * 0.70710678118654752f)); // exact gelu
    return v;
}

__device__ inline float wave_sum(float v) {
#pragma unroll
    for (int off = 32; off > 0; off >>= 1) v += __shfl_xor(v, off, 64);
    return v;
}

// ---------------- h = (1+eps)*x ----------------
__global__ void init_h_kernel(const float* __restrict__ x, const float* __restrict__ eps,
                              float* __restrict__ h, int total) {
    int i = blockIdx.x * 256 + threadIdx.x;
    if (i < total) h[i] = (1.f + eps[0]) * x[i];
}

// ---------------- GINE edge kernel ----------------
__global__ __launch_bounds__(256) void edge_kernel(
        const float* __restrict__ x, const int* __restrict__ ei,
        const float* __restrict__ ea, const float* __restrict__ Wl,
        const float* __restrict__ bl, float* __restrict__ h, int E) {
    __shared__ float s_ea[EPB][ED];
    __shared__ int s_src[EPB], s_dst[EPB];
    int tid = threadIdx.x;
    int e0 = blockIdx.x * EPB;
    float w[ED];
#pragma unroll
    for (int k = 0; k < ED; k++) w[k] = Wl[k * D + tid];
    float bld = bl[tid];
    for (int i = tid; i < EPB * ED; i += 256) {
        int e = i >> 6, c = i & 63;
        s_ea[e][c] = ea[(size_t)(e0 + e) * ED + c];
    }
    if (tid < EPB) { s_src[tid] = ei[e0 + tid]; s_dst[tid] = ei[E + e0 + tid]; }
    __syncthreads();
    for (int i = 0; i < EPB; i++) {
        const float4* eap = (const float4*)&s_ea[i][0];
        float v = bld;
#pragma unroll
        for (int k4 = 0; k4 < ED / 4; k4++) {
            float4 e4 = eap[k4];
            v += e4.x * w[k4 * 4] + e4.y * w[k4 * 4 + 1] + e4.z * w[k4 * 4 + 2] + e4.w * w[k4 * 4 + 3];
        }
        float m = v + x[(size_t)s_src[i] * D + tid];
        m = fmaxf(m, 0.f);
        atomicAdd(&h[(size_t)s_dst[i] * D + tid], m);
    }
}

// ---------------- generic fp32 GEMM ----------------
#define BM 64
#define BN 64
#define BK 16
template<int ACT, bool TRANSB>
__global__ __launch_bounds__(256) void gemm_kernel(
        const float* __restrict__ A, const float* __restrict__ B,
        const float* __restrict__ bias, float* __restrict__ C,
        int M, int K, int Nc) {
    __shared__ float As[BK][BM + 4];
    __shared__ float Bs[BK][BN + 4];
    int tid = threadIdx.x;
    int m0 = blockIdx.y * BM, n0 = blockIdx.x * BN;
    int tm = (tid >> 4) * 4, tn = (tid & 15) * 4;
    float acc[4][4] = {};
    for (int k0 = 0; k0 < K; k0 += BK) {
        int ac = tid & 15, ar = tid >> 4;
#pragma unroll
        for (int p = 0; p < 4; p++)
            As[ac][ar + p * 16] = A[(size_t)(m0 + ar + p * 16) * K + k0 + ac];
        if (TRANSB) {
            int bk = tid & 15, bj = tid >> 4;
#pragma unroll
            for (int p = 0; p < 4; p++)
                Bs[bk][bj + p * 16] = B[(size_t)(n0 + bj + p * 16) * K + k0 + bk];
        } else {
            int bj = tid & 63, bk = tid >> 6;
#pragma unroll
            for (int p = 0; p < 4; p++)
                Bs[bk + p * 4][bj] = B[(size_t)(k0 + bk + p * 4) * Nc + n0 + bj];
        }
        __syncthreads();
#pragma unroll
        for (int k = 0; k < BK; k++) {
            float4 a4 = *(const float4*)&As[k][tm];
            float4 b4 = *(const float4*)&Bs[k][tn];
            float a[4] = {a4.x, a4.y, a4.z, a4.w};
            float b[4] = {b4.x, b4.y, b4.z, b4.w};
#pragma unroll
            for (int i = 0; i < 4; i++)
#pragma unroll
                for (int j = 0; j < 4; j++) acc[i][j] += a[i] * b[j];
        }
        __syncthreads();
    }
#pragma unroll
    for (int i = 0; i < 4; i++) {
        float4 r;
        r.x = act_f<ACT>(acc[i][0] + bias[n0 + tn + 0]);
        r.y = act_f<ACT>(acc[i][1] + bias[n0 + tn + 1]);
        r.z = act_f<ACT>(acc[i][2] + bias[n0 + tn + 2]);
        r.w = act_f<ACT>(acc[i][3] + bias[n0 + tn + 3]);
        *(float4*)&C[(size_t)(m0 + tm + i) * Nc + n0 + tn] = r;
    }
}

// ---------------- row LayerNorm + optional ELU + residual ----------------
template<int ACT>
__global__ __launch_bounds__(256) void ln_res_kernel(
        const float* __restrict__ t, const float* __restrict__ res,
        const float* __restrict__ g, const float* __restrict__ b,
        float* __restrict__ out) {
    __shared__ float red[8];
    int row = blockIdx.x, tid = threadIdx.x;
    float v = t[(size_t)row * D + tid];
    int wid = tid >> 6, lane = tid & 63;
    float s = wave_sum(v);
    if (lane == 0) red[wid] = s;
    __syncthreads();
    float mu = (red[0] + red[1] + red[2] + red[3]) * (1.f / D);
    float dv = v - mu;
    float s2 = wave_sum(dv * dv);
    if (lane == 0) red[4 + wid] = s2;
    __syncthreads();
    float var = (red[4] + red[5] + red[6] + red[7]) * (1.f / D);
    float y = dv * rsqrtf(var + 1e-5f) * g[tid] + b[tid];
    y = act_f<ACT>(y);
    out[(size_t)row * D + tid] = res[(size_t)row * D + tid] + y;
}

// ---------------- MFMA flash attention (split-K partials) ----------------
// Computes S^T = K.Q^T per 16q x 32k step with a permuted key->M mapping so the
// MFMA C-layout leaves each lane holding P[q=lane&15][k=quad*8+j] -- exactly the
// B-operand layout for the PV MFMA (O^T = V^T.P^T). Softmax state per-lane.
#define KSTR 40     // Ks row stride (bf16 elems), 80B: 16B-aligned, bank-spread
#define VSTR 136    // VTs row stride, 272B: 16B-aligned
#define ATILE 128
__global__ __launch_bounds__(256) void attn_mfma_kernel(
        const float* __restrict__ qkv, float* __restrict__ po,
        float* __restrict__ pm, float* __restrict__ pl, int N, int KC_) {
    __shared__ short Ks[ATILE * KSTR];
    __shared__ short VTs[HD * VSTR];
    const int tid = threadIdx.x;
    const int wave = tid >> 6, lane = tid & 63;
    const int mm = lane & 15, quad = lane >> 4;
    const int h = blockIdx.y, c = blockIdx.z;
    const int qbase = blockIdx.x * 64 + wave * 16;
    const float scale = 0.17677669529663687f; // 1/sqrt(32)

    // Q fragment (B operand): qf[j] = Q[qbase+mm][quad*8+j] * scale
    short8 qf;
    {
        const float* qrow = qkv + (size_t)(qbase + mm) * (3 * D) + h * HD + quad * 8;
        float4 a = *(const float4*)qrow;
        float4 b = *(const float4*)(qrow + 4);
        qf[0] = f2bf(a.x * scale); qf[1] = f2bf(a.y * scale);
        qf[2] = f2bf(a.z * scale); qf[3] = f2bf(a.w * scale);
        qf[4] = f2bf(b.x * scale); qf[5] = f2bf(b.y * scale);
        qf[6] = f2bf(b.z * scale); qf[7] = f2bf(b.w * scale);
    }
    floatx4 accA = {0.f, 0.f, 0.f, 0.f};  // O[q][quad*4+reg]
    floatx4 accB = {0.f, 0.f, 0.f, 0.f};  // O[q][16+quad*4+reg]
    float m_r = -1e30f, l_r = 0.f;

    const int kchunk = N / KC_;
    const int kstart = c * kchunk;
    const int krow0 = ((mm >> 2) << 3) | (mm & 3);   // key-permuted M mapping

    for (int t0 = 0; t0 < kchunk; t0 += ATILE) {
        // stage K rows (bf16) and V transposed (bf16)
#pragma unroll
        for (int p = 0; p < 4; p++) {
            int slot = tid + p * 256;        // 1024 float4 slots
            int kr = slot >> 3, e4 = slot & 7;
            const float* krow = qkv + (size_t)(kstart + t0 + kr) * (3 * D) + D + h * HD + e4 * 4;
            float4 kv = *(const float4*)krow;
            short4v ks;
            ks[0] = f2bf(kv.x); ks[1] = f2bf(kv.y); ks[2] = f2bf(kv.z); ks[3] = f2bf(kv.w);
            *(short4v*)&Ks[kr * KSTR + e4 * 4] = ks;
            const float* vrow = qkv + (size_t)(kstart + t0 + kr) * (3 * D) + 2 * D + h * HD + e4 * 4;
            float4 vv = *(const float4*)vrow;
            VTs[(e4 * 4 + 0) * VSTR + kr] = f2bf(vv.x);
            VTs[(e4 * 4 + 1) * VSTR + kr] = f2bf(vv.y);
            VTs[(e4 * 4 + 2) * VSTR + kr] = f2bf(vv.z);
            VTs[(e4 * 4 + 3) * VSTR + kr] = f2bf(vv.w);
        }
        __syncthreads();
#pragma unroll
        for (int s = 0; s < ATILE / 32; s++) {
            int sb = s * 32;
            short8 kf0 = *(const short8*)&Ks[(sb + krow0) * KSTR + quad * 8];
            short8 kf1 = *(const short8*)&Ks[(sb + krow0 + 4) * KSTR + quad * 8];
            floatx4 zero = {0.f, 0.f, 0.f, 0.f};
            floatx4 s0 = __builtin_amdgcn_mfma_f32_16x16x32_bf16(kf0, qf, zero, 0, 0, 0);
            floatx4 s1 = __builtin_amdgcn_mfma_f32_16x16x32_bf16(kf1, qf, zero, 0, 0, 0);
            // lane holds scores for q=mm at keys sb+quad*8+{0..3} (s0) and +{4..7} (s1)
            float mx = fmaxf(fmaxf(fmaxf(s0[0], s0[1]), fmaxf(s0[2], s0[3])),
                             fmaxf(fmaxf(s1[0], s1[1]), fmaxf(s1[2], s1[3])));
            mx = fmaxf(mx, __shfl_xor(mx, 16));
            mx = fmaxf(mx, __shfl_xor(mx, 32));
            float nm = fmaxf(m_r, mx);
            float alpha = __expf(m_r - nm);
            float p0[4], p1[4], ls = 0.f;
#pragma unroll
            for (int j = 0; j < 4; j++) {
                p0[j] = __expf(s0[j] - nm);
                p1[j] = __expf(s1[j] - nm);
                ls += p0[j] + p1[j];
            }
            ls += __shfl_xor(ls, 16);
            ls += __shfl_xor(ls, 32);
            l_r = l_r * alpha + ls;
            m_r = nm;
            short8 pf;
#pragma unroll
            for (int j = 0; j < 4; j++) { pf[j] = f2bf(p0[j]); pf[4 + j] = f2bf(p1[j]); }
#pragma unroll
            for (int j = 0; j < 4; j++) { accA[j] *= alpha; accB[j] *= alpha; }
            short8 vf0 = *(const short8*)&VTs[mm * VSTR + sb + quad * 8];
            short8 vf1 = *(const short8*)&VTs[(mm + 16) * VSTR + sb + quad * 8];
            accA = __builtin_amdgcn_mfma_f32_16x16x32_bf16(vf0, pf, accA, 0, 0, 0);
            accB = __builtin_amdgcn_mfma_f32_16x16x32_bf16(vf1, pf, accB, 0, 0, 0);
        }
        __syncthreads();
    }
    size_t NH = (size_t)N * H;
    int qi = qbase + mm;
    size_t nh = (size_t)qi * H + h;
    if (lane < 16) {
        pm[(size_t)c * NH + nh] = m_r;
        pl[(size_t)c * NH + nh] = l_r;
    }
    float* op = po + ((size_t)c * NH + nh) * HD;
#pragma unroll
    for (int j = 0; j < 4; j++) {
        op[quad * 4 + j] = accA[j];
        op[16 + quad * 4 + j] = accB[j];
    }
}

// ---------------- combine partials -> obuf[N, 256] ----------------
__global__ __launch_bounds__(256) void attn_combine_kernel(
        const float* __restrict__ po, const float* __restrict__ pm,
        const float* __restrict__ pl, float* __restrict__ obuf, int N, int KC_) {
    int idx = blockIdx.x * 256 + threadIdx.x;   // over N*H*HD
    int d = idx & (HD - 1);
    int nh = idx >> 5;
    size_t NH = (size_t)N * H;
    float M = -1e30f;
    for (int cc = 0; cc < KC_; cc++) M = fmaxf(M, pm[(size_t)cc * NH + nh]);
    float l = 0.f, o = 0.f;
    for (int cc = 0; cc < KC_; cc++) {
        float a = __expf(pm[(size_t)cc * NH + nh] - M);
        l += a * pl[(size_t)cc * NH + nh];
        o += a * po[((size_t)cc * NH + nh) * HD + d];
    }
    int n = nh >> 3, h = nh & (H - 1);
    obuf[(size_t)n * D + h * HD + d] = o / l;
}

// ---------------- launch ----------------
extern "C" void kernel_launch(void* const* d_in, const int* in_sizes, int n_in,
                              void* d_out, int out_size, void* d_ws, size_t ws_size,
                              hipStream_t stream) {
    const float* x    = (const float*)d_in[0];
    const int*   ei   = (const int*)d_in[1];
    const float* ea   = (const float*)d_in[2];
    const float* eps  = (const float*)d_in[3];
    const float* Wl   = (const float*)d_in[4];
    const float* bl   = (const float*)d_in[5];
    const float* W1   = (const float*)d_in[6];
    const float* b1   = (const float*)d_in[7];
    const float* W2   = (const float*)d_in[8];
    const float* b2   = (const float*)d_in[9];
    const float* lnlg = (const float*)d_in[10];
    const float* lnlb = (const float*)d_in[11];
    const float* in_w = (const float*)d_in[12];
    const float* in_b = (const float*)d_in[13];
    const float* outw = (const float*)d_in[14];
    const float* outb = (const float*)d_in[15];
    const float* lnag = (const float*)d_in[16];
    const float* lnab = (const float*)d_in[17];
    const float* Wf1  = (const float*)d_in[18];
    const float* bf1  = (const float*)d_in[19];
    const float* Wf2  = (const float*)d_in[20];
    const float* bf2  = (const float*)d_in[21];
    const float* lnfg = (const float*)d_in[22];
    const float* lnfb = (const float*)d_in[23];
    float* out = (float*)d_out;

    const int N = in_sizes[0] / D;       // 4096
    const int E = in_sizes[1] / 2;       // 262144
    const size_t NF = (size_t)N * D;     // 1048576

    auto need_bytes = [&](int kc) -> size_t {
        return ((size_t)(4 + kc) * NF + 2 * (size_t)kc * N * H) * sizeof(float);
    };
    int KCsel = (ws_size >= need_bytes(4)) ? 4 : 2;

    float* w = (float*)d_ws;
    float* x1   = w;
    float* qkv  = w + NF;
    float* h    = w + 4 * NF;
    float* t1   = w + 5 * NF;
    float* t2   = w + 6 * NF;
    float* po   = w + 4 * NF;
    float* pm   = w + (4 + (size_t)KCsel) * NF;
    float* pl   = pm + (size_t)KCsel * N * H;
    float* obuf = w + NF;
    float* t3   = w + 2 * NF;
    float* x2   = w + 3 * NF;
    float* f1   = w + 4 * NF;
    float* f2   = w + 6 * NF;

    // 1. h = (1+eps)*x
    init_h_kernel<<<(int)(NF / 256), 256, 0, stream>>>(x, eps, h, (int)NF);
    // 2. GINE scatter
    edge_kernel<<<E / EPB, 256, 0, stream>>>(x, ei, ea, Wl, bl, h, E);
    // 3. t1 = elu(h@W1+b1)
    gemm_kernel<2, false><<<dim3(D / BN, N / BM), 256, 0, stream>>>(h, W1, b1, t1, N, D, D);
    // 4. t2 = t1@W2+b2
    gemm_kernel<0, false><<<dim3(D / BN, N / BM), 256, 0, stream>>>(t1, W2, b2, t2, N, D, D);
    // 5. x1 = x + elu(ln(t2))
    ln_res_kernel<2><<<N, 256, 0, stream>>>(t2, x, lnlg, lnlb, x1);
    // 6. qkv = x1 @ in_w.T + in_b
    gemm_kernel<0, true><<<dim3(3 * D / BN, N / BM), 256, 0, stream>>>(x1, in_w, in_b, qkv, N, D, 3 * D);
    // 7. attention partials (MFMA flash)
    attn_mfma_kernel<<<dim3(N / 64, H, KCsel), 256, 0, stream>>>(qkv, po, pm, pl, N, KCsel);
    // 8. combine
    attn_combine_kernel<<<(int)(NF / 256), 256, 0, stream>>>(po, pm, pl, obuf, N, KCsel);
    // 9. t3 = obuf @ out_w.T + out_b
    gemm_kernel<0, true><<<dim3(D / BN, N / BM), 256, 0, stream>>>(obuf, outw, outb, t3, N, D, D);
    // 10. x2 = x1 + ln(t3)
    ln_res_kernel<0><<<N, 256, 0, stream>>>(t3, x1, lnag, lnab, x2);
    // 11. f1 = gelu(x2@Wf1+bf1)
    gemm_kernel<3, false><<<dim3(2 * D / BN, N / BM), 256, 0, stream>>>(x2, Wf1, bf1, f1, N, D, 2 * D);
    // 12. f2 = f1@Wf2+bf2
    gemm_kernel<0, false><<<dim3(D / BN, N / BM), 256, 0, stream>>>(f1, Wf2, bf2, f2, N, 2 * D, D);
    // 13. out = x2 + ln(f2)
    ln_res_kernel<0><<<N, 256, 0, stream>>>(f2, x2, lnfg, lnfb, out);

    (void)n_in; (void)out_size; (void)ws_size;
}